// Round 5
// baseline (347.574 us; speedup 1.0000x reference)
//
#include <hip/hip_runtime.h>
#include <hip/hip_bf16.h>

#define BDIM 2
#define SDIM 1024
#define DDIM 2048
#define NH 16
#define NKV 8
#define HD 128
#define WINDOW 256

typedef __bf16 bf16;
typedef __bf16 bf16x4 __attribute__((ext_vector_type(4)));
typedef __bf16 bf16x8 __attribute__((ext_vector_type(8)));
typedef float f32x4 __attribute__((ext_vector_type(4)));

#define L2E 1.44269504088896341f

__device__ inline bf16x8 load8(const bf16* p) { return *reinterpret_cast<const bf16x8*>(p); }

// async global->LDS, 16 B per lane (wave-uniform base + lane*16 contract)
__device__ __forceinline__ void gl_lds16(const bf16* g, bf16* l) {
  __builtin_amdgcn_global_load_lds(
      (__attribute__((address_space(1))) void*)g,
      (__attribute__((address_space(3))) void*)l,
      16, 0, 0);
}

// ---------------- fp32 -> bf16 cast (8 elems/thread) ----------------
__global__ __launch_bounds__(256) void cast_f32_bf16(const float* __restrict__ src,
                                                     bf16* __restrict__ dst) {
  long i = ((long)blockIdx.x * 256 + threadIdx.x) * 8;
  float4 a = *(const float4*)(src + i);
  float4 b = *(const float4*)(src + i + 4);
  bf16x8 o;
  o[0] = (bf16)a.x; o[1] = (bf16)a.y; o[2] = (bf16)a.z; o[3] = (bf16)a.w;
  o[4] = (bf16)b.x; o[5] = (bf16)b.y; o[6] = (bf16)b.z; o[7] = (bf16)b.w;
  *(bf16x8*)(dst + i) = o;
}

// ---------------- fused weight transposes (fp32 in, bf16 out) ----------------
// z: 0=wq, 1=wk, 2=wv, 3=wo. dst[C][R] = src[R][C], R=2048.
__global__ __launch_bounds__(256) void wtrans_all(const float* __restrict__ wq,
                                                  const float* __restrict__ wk,
                                                  const float* __restrict__ wv,
                                                  const float* __restrict__ wo,
                                                  bf16* __restrict__ wqkvT,
                                                  bf16* __restrict__ woT) {
  __shared__ bf16 tile[32][33];
  int z = blockIdx.z;
  const float* src; bf16* dst; int C;
  if (z == 0)      { src = wq; dst = wqkvT;                 C = 2048; }
  else if (z == 1) { src = wk; dst = wqkvT + 2048L * 2048;  C = 1024; }
  else if (z == 2) { src = wv; dst = wqkvT + 3072L * 2048;  C = 1024; }
  else             { src = wo; dst = woT;                   C = 2048; }
  int c0 = blockIdx.x * 32, r0 = blockIdx.y * 32;
  if (c0 >= C) return;
  int x = threadIdx.x, y = threadIdx.y;  // 32 x 8
  for (int yy = y; yy < 32; yy += 8)
    tile[yy][x] = (bf16)src[(long)(r0 + yy) * C + c0 + x];
  __syncthreads();
  for (int yy = y; yy < 32; yy += 8)
    dst[(long)(c0 + yy) * 2048 + r0 + x] = tile[x][yy];
}

// ---------------- V transpose per (b,kv): vT[z][d][s] = v[b][s][kv][d] (bf16) ----------------
__global__ __launch_bounds__(256) void vtrans(const bf16* __restrict__ qkv,
                                              bf16* __restrict__ vT) {
  __shared__ bf16 tile[32][33];
  int s0 = blockIdx.x * 32, d0 = blockIdx.y * 32;
  int z = blockIdx.z;
  int b = z >> 3, kv = z & 7;
  const bf16* src = qkv + ((long)b * SDIM) * 4096 + 3072 + kv * 128;
  bf16* dst = vT + (long)z * 128 * 1024;
  int x = threadIdx.x, y = threadIdx.y;
  for (int yy = y; yy < 32; yy += 8)
    tile[yy][x] = src[(long)(s0 + yy) * 4096 + d0 + x];
  __syncthreads();
  for (int yy = y; yy < 32; yy += 8)
    dst[(long)(d0 + yy) * 1024 + s0 + x] = tile[x][yy];
}

// ---------------- GEMM (m97 structure): C[M][N] = A * Bt^T, global_load_lds staging ----------------
#define BK 64
template <typename OT>
__global__ __launch_bounds__(256) void gemm_bt_lds(const bf16* __restrict__ A,
                                                   const bf16* __restrict__ Bt,
                                                   OT* __restrict__ C,
                                                   int M, int N, int K) {
  __shared__ bf16 As[128 * BK];  // unpadded: global_load_lds needs contiguous lane order
  __shared__ bf16 Bs[128 * BK];
  int m0 = blockIdx.y * 128, n0 = blockIdx.x * 128;
  int t = threadIdx.x;
  int wid = t >> 6, lane = t & 63;
  int wm = (wid >> 1) * 64, wn = (wid & 1) * 64;
  int fm = lane & 15, quad = lane >> 4;
  f32x4 acc[4][4] = {};
  for (int k0 = 0; k0 < K; k0 += BK) {
    for (int p = 0; p < 4; ++p) {
      int idx = p * 256 + t;
      int row = idx >> 3, cg = (idx & 7) * 8;
      gl_lds16(&A[(long)(m0 + row) * K + k0 + cg], &As[idx * 8]);
      gl_lds16(&Bt[(long)(n0 + row) * K + k0 + cg], &Bs[idx * 8]);
    }
    __syncthreads();
    for (int ks = 0; ks < BK; ks += 32) {
      bf16x8 af[4], bfr[4];
      for (int i = 0; i < 4; ++i) af[i] = load8(&As[(wm + i * 16 + fm) * BK + ks + quad * 8]);
      for (int i = 0; i < 4; ++i) bfr[i] = load8(&Bs[(wn + i * 16 + fm) * BK + ks + quad * 8]);
      for (int i = 0; i < 4; ++i)
        for (int j = 0; j < 4; ++j)
          acc[i][j] = __builtin_amdgcn_mfma_f32_16x16x32_bf16(af[i], bfr[j], acc[i][j], 0, 0, 0);
    }
    __syncthreads();
  }
  for (int i = 0; i < 4; ++i)
    for (int j = 0; j < 4; ++j)
      for (int r = 0; r < 4; ++r) {
        int row = m0 + wm + i * 16 + quad * 4 + r;
        int col = n0 + wn + j * 16 + fm;
        C[(long)row * N + col] = (OT)acc[i][j][r];
      }
}

// ---------------- fused RoPE: Q -> q1,q2 (pre-scaled) and K -> k1 ----------------
__global__ __launch_bounds__(256) void rope_qk(const bf16* __restrict__ qkv,
                                               const float* __restrict__ fc,
                                               const float* __restrict__ fs,
                                               bf16* __restrict__ q1,
                                               bf16* __restrict__ q2,
                                               bf16* __restrict__ k1) {
  int idx = blockIdx.x * 256 + threadIdx.x;
  if (idx < 2 * 1024 * 1024) {  // Q part
    int row = idx >> 10;
    int rem = idx & 1023;
    int h = rem >> 6, d = rem & 63;
    int s = row & (SDIM - 1);
    long src = (long)row * 4096 + h * 128 + 2 * d;
    float xr = (float)qkv[src], xi = (float)qkv[src + 1];
    const float scale = 0.08838834764831845f;  // 1/sqrt(128)
    float c = fc[s * 64 + d], sn = fs[s * 64 + d];
    long dst = (long)row * 2048 + h * 128 + 2 * d;
    q1[dst]     = (bf16)((xr * c - xi * sn) * scale);
    q1[dst + 1] = (bf16)((xr * sn + xi * c) * scale);
    float cw = fc[WINDOW * 64 + d], sw = fs[WINDOW * 64 + d];
    q2[dst]     = (bf16)((xr * cw - xi * sw) * scale);
    q2[dst + 1] = (bf16)((xr * sw + xi * cw) * scale);
  } else {  // K part
    int i2 = idx - 2 * 1024 * 1024;
    int row = i2 >> 9;
    int rem = i2 & 511;
    int kv = rem >> 6, d = rem & 63;
    int s = row & (SDIM - 1);
    long src = (long)row * 4096 + 2048 + kv * 128 + 2 * d;
    float xr = (float)qkv[src], xi = (float)qkv[src + 1];
    float c = fc[s * 64 + d], sn = fs[s * 64 + d];
    long dst = (long)row * 1024 + kv * 128 + 2 * d;
    k1[dst]     = (bf16)(xr * c - xi * sn);
    k1[dst + 1] = (bf16)(xr * sn + xi * c);
  }
}

// ---------------- Flash attention v5: 512 wgs, reg-prefetch pipeline ----------------
// Grid (16, NH, B): tile = x (b=0) or 15-x (b=1) so each CU's 2 wgs sum to 17 blocks.
#define KPITCH 136
#define VPITCH 72
#define PPITCH 72
__global__ __launch_bounds__(256, 2) void attn_kernel(const bf16* __restrict__ q1,
                                                      const bf16* __restrict__ q2,
                                                      const bf16* __restrict__ k1,
                                                      const bf16* __restrict__ qkv,
                                                      const bf16* __restrict__ vT,
                                                      bf16* __restrict__ aout) {
  __shared__ bf16 Ks[128][KPITCH];   // rows 0-63: roped K1; rows 64-127: raw K2
  __shared__ bf16 VTs[128][VPITCH];  // [d][key]
  __shared__ bf16 Pl[4][16][PPITCH]; // per-wave P[q][k]
  __shared__ float stats[4][16];

  int h = blockIdx.y;
  int b = blockIdx.z;
  int tile = b ? (15 - blockIdx.x) : blockIdx.x;
  int kv = h >> 1;  // NREP = 2
  int t = threadIdx.x;
  int w = t >> 6, lane = t & 63;
  int m = lane & 15, quad = lane >> 4;

  const bf16* k1g0 = k1 + ((long)b * SDIM) * 1024 + kv * 128;
  const bf16* k2g0 = qkv + ((long)b * SDIM) * 4096 + 2048 + kv * 128;
  const bf16* vtg0 = vT + ((long)(b * NKV + kv)) * 128 * 1024;

  int t0 = tile * 64;
  int i0w = t0 + w * 16;  // this wave's 16 query rows

  const bf16* q1p = q1 + ((long)(b * SDIM + i0w + m)) * 2048 + h * 128 + quad * 8;
  const bf16* q2p = q2 + ((long)(b * SDIM + i0w + m)) * 2048 + h * 128 + quad * 8;
  bf16x8 q1f[4], q2f[4];
  for (int kc = 0; kc < 4; ++kc) {
    q1f[kc] = load8(q1p + kc * 32);
    q2f[kc] = load8(q2p + kc * 32);
  }

  f32x4 o[8] = {};
  float mrow = -INFINITY, lrow = 0.f;  // per-lane: row q = i0w + m

  // staging decomposition (per thread): K tiles 4x16B chunks, V tile 4x16B chunks
  int krow = t >> 4, kcol = (t & 15) * 8;  // + p*16 rows
  int vrow = t >> 3, vcol = (t & 7) * 8;   // + p*32 rows
  uint4 pk1[4], pk2[4], pv[4];

  // prefetch block 0
  bool c1 = (63 > t0 - WINDOW);
  bool c2 = (0 <= t0 + 63 - WINDOW);
  {
    for (int p = 0; p < 4; ++p) {
      int r = p * 16 + krow, vr = p * 32 + vrow;
      if (c1) pk1[p] = *(const uint4*)&k1g0[(long)r * 1024 + kcol];
      if (c2) pk2[p] = *(const uint4*)&k2g0[(long)r * 4096 + kcol];
      pv[p] = *(const uint4*)&vtg0[(long)vr * 1024 + vcol];
    }
  }

  for (int j0 = 0; j0 < t0 + 64; j0 += 64) {
    __syncthreads();  // prior compute done reading LDS
    for (int p = 0; p < 4; ++p) {
      int r = p * 16 + krow, vr = p * 32 + vrow;
      if (c1) *(uint4*)&Ks[r][kcol] = pk1[p];
      if (c2) *(uint4*)&Ks[64 + r][kcol] = pk2[p];
      *(uint4*)&VTs[vr][vcol] = pv[p];
    }
    __syncthreads();

    // prefetch next block while computing current
    int j0n = j0 + 64;
    bool n1 = false, n2 = false;
    if (j0n < t0 + 64) {
      n1 = (j0n + 63 > t0 - WINDOW);
      n2 = (j0n <= t0 + 63 - WINDOW);
      for (int p = 0; p < 4; ++p) {
        int r = p * 16 + krow, vr = p * 32 + vrow;
        if (n1) pk1[p] = *(const uint4*)&k1g0[(long)(j0n + r) * 1024 + kcol];
        if (n2) pk2[p] = *(const uint4*)&k2g0[(long)(j0n + r) * 4096 + kcol];
        pv[p] = *(const uint4*)&vtg0[(long)vr * 1024 + j0n + vcol];
      }
    }

    if (j0 < i0w + 16) {  // wave-uniform: block has unmasked keys for this wave
      bool need1 = (j0 + 63 > i0w - WINDOW);
      bool need2 = (j0 <= i0w + 15 - WINDOW);
      f32x4 s1[4] = {}, s2[4] = {};
      if (need1)
        for (int st = 0; st < 4; ++st)
          for (int kc = 0; kc < 4; ++kc)
            s1[st] = __builtin_amdgcn_mfma_f32_16x16x32_bf16(
                load8(&Ks[st * 16 + m][kc * 32 + quad * 8]), q1f[kc], s1[st], 0, 0, 0);
      if (need2)
        for (int st = 0; st < 4; ++st)
          for (int kc = 0; kc < 4; ++kc)
            s2[st] = __builtin_amdgcn_mfma_f32_16x16x32_bf16(
                load8(&Ks[64 + st * 16 + m][kc * 32 + quad * 8]), q2f[kc], s2[st], 0, 0, 0);
      // select + mask; element (st,r): row i = i0w+m, col j = j0+16*st+4*quad+r
      int i = i0w + m;
      float sv[4][4];
      for (int st = 0; st < 4; ++st)
        for (int r = 0; r < 4; ++r) {
          int j = j0 + st * 16 + quad * 4 + r;
          float v;
          if (j > i) v = -INFINITY;
          else if (j > i - WINDOW) v = s1[st][r];
          else v = s2[st][r];
          sv[st][r] = v;
        }
      // row reduce: in-lane (16 vals) + 2 shuffles
      float bm = -INFINITY;
      for (int st = 0; st < 4; ++st)
        for (int r = 0; r < 4; ++r) bm = fmaxf(bm, sv[st][r]);
      bm = fmaxf(bm, __shfl_xor(bm, 16, 64));
      bm = fmaxf(bm, __shfl_xor(bm, 32, 64));
      float mnew = fmaxf(mrow, bm);
      float alpha = exp2f((mrow - mnew) * L2E);
      float rs = 0.f;
      for (int st = 0; st < 4; ++st) {
        bf16x4 pk;
        for (int r = 0; r < 4; ++r) {
          float pvv = exp2f((sv[st][r] - mnew) * L2E);
          rs += pvv;
          pk[r] = (bf16)pvv;
        }
        *(bf16x4*)&Pl[w][m][st * 16 + quad * 4] = pk;  // b64 write
      }
      rs += __shfl_xor(rs, 16, 64);
      rs += __shfl_xor(rs, 32, 64);
      lrow = lrow * alpha + rs;
      mrow = mnew;
      // broadcast alpha to C-layout rows
      if (lane < 16) stats[w][lane] = alpha;
      f32x4 av = *(f32x4*)&stats[w][quad * 4];
      for (int n8 = 0; n8 < 8; ++n8)
        for (int r = 0; r < 4; ++r) o[n8][r] *= av[r];
      // PV: O += P * V
      for (int kc = 0; kc < 2; ++kc) {
        bf16x8 af = load8(&Pl[w][m][kc * 32 + quad * 8]);
        for (int n8 = 0; n8 < 8; ++n8)
          o[n8] = __builtin_amdgcn_mfma_f32_16x16x32_bf16(
              af, load8(&VTs[n8 * 16 + m][kc * 32 + quad * 8]), o[n8], 0, 0, 0);
      }
    }
    c1 = n1; c2 = n2;
  }

  // epilogue: redistribute l to C-layout rows, normalize, store
  if (lane < 16) stats[w][lane] = lrow;
  f32x4 lv = *(f32x4*)&stats[w][quad * 4];
  for (int n8 = 0; n8 < 8; ++n8)
    for (int r = 0; r < 4; ++r) {
      int row = i0w + quad * 4 + r;
      float val = o[n8][r] / lv[r];
      aout[((long)(b * SDIM + row)) * 2048 + h * 128 + n8 * 16 + m] = (bf16)val;
    }
}

extern "C" void kernel_launch(void* const* d_in, const int* in_sizes, int n_in,
                              void* d_out, int out_size, void* d_ws, size_t ws_size,
                              hipStream_t stream) {
  const float* x  = (const float*)d_in[0];
  const float* fc = (const float*)d_in[1];
  const float* fs = (const float*)d_in[2];
  const float* wq = (const float*)d_in[3];
  const float* wk = (const float*)d_in[4];
  const float* wv = (const float*)d_in[5];
  const float* wo = (const float*)d_in[6];
  float* out = (float*)d_out;

  // workspace layout (bf16 elements)
  bf16* wqkvT = (bf16*)d_ws;                  // [4096][2048]
  bf16* woT   = wqkvT + 4096L * 2048;         // [2048][2048]
  bf16* xb    = woT + 2048L * 2048;           // [2048][2048]
  bf16* qkv   = xb + 2048L * 2048;            // [2048][4096]
  bf16* q1    = qkv + 2048L * 4096;           // [2048][2048]
  bf16* q2    = q1 + 2048L * 2048;            // [2048][2048]
  bf16* k1b   = q2 + 2048L * 2048;            // [2048][1024]
  bf16* vT    = k1b + 2048L * 1024;           // [16][128][1024]
  bf16* aout  = vT + 2048L * 1024;            // [2048][2048]

  cast_f32_bf16<<<2048, 256, 0, stream>>>(x, xb);
  wtrans_all<<<dim3(64, 64, 4), dim3(32, 8), 0, stream>>>(wq, wk, wv, wo, wqkvT, woT);

  gemm_bt_lds<bf16><<<dim3(32, 16), 256, 0, stream>>>(xb, wqkvT, qkv, 2048, 4096, 2048);

  rope_qk<<<12288, 256, 0, stream>>>(qkv, fc, fs, q1, q2, k1b);
  vtrans<<<dim3(32, 4, 16), dim3(32, 8), 0, stream>>>(qkv, vT);

  attn_kernel<<<dim3(16, 16, 2), 256, 0, stream>>>(q1, q2, k1b, qkv, vT, aout);

  gemm_bt_lds<float><<<dim3(16, 16), 256, 0, stream>>>(aout, woT, out, 2048, 2048, 2048);
}

// Round 6
// 259.978 us; speedup vs baseline: 1.3369x; 1.3369x over previous
//
#include <hip/hip_runtime.h>
#include <hip/hip_bf16.h>

#define BDIM 2
#define SDIM 1024
#define DDIM 2048
#define NH 16
#define NKV 8
#define HD 128
#define WINDOW 256

typedef __bf16 bf16;
typedef __bf16 bf16x4 __attribute__((ext_vector_type(4)));
typedef __bf16 bf16x8 __attribute__((ext_vector_type(8)));
typedef float f32x4 __attribute__((ext_vector_type(4)));

#define L2E 1.44269504088896341f

__device__ inline bf16x8 load8(const bf16* p) { return *reinterpret_cast<const bf16x8*>(p); }

// async global->LDS, 16 B per lane (LDS dest = wave-uniform base + lane*16)
__device__ __forceinline__ void gl_lds16(const bf16* g, bf16* l) {
  __builtin_amdgcn_global_load_lds(
      (__attribute__((address_space(1))) void*)g,
      (__attribute__((address_space(3))) void*)l,
      16, 0, 0);
}

// ---------------- fp32 -> bf16 cast (8 elems/thread) ----------------
__global__ __launch_bounds__(256) void cast_f32_bf16(const float* __restrict__ src,
                                                     bf16* __restrict__ dst) {
  long i = ((long)blockIdx.x * 256 + threadIdx.x) * 8;
  float4 a = *(const float4*)(src + i);
  float4 b = *(const float4*)(src + i + 4);
  bf16x8 o;
  o[0] = (bf16)a.x; o[1] = (bf16)a.y; o[2] = (bf16)a.z; o[3] = (bf16)a.w;
  o[4] = (bf16)b.x; o[5] = (bf16)b.y; o[6] = (bf16)b.z; o[7] = (bf16)b.w;
  *(bf16x8*)(dst + i) = o;
}

// ---------------- fused weight transposes (fp32 in, bf16 out) ----------------
__global__ __launch_bounds__(256) void wtrans_all(const float* __restrict__ wq,
                                                  const float* __restrict__ wk,
                                                  const float* __restrict__ wv,
                                                  const float* __restrict__ wo,
                                                  bf16* __restrict__ wqkvT,
                                                  bf16* __restrict__ woT) {
  __shared__ bf16 tile[32][33];
  int z = blockIdx.z;
  const float* src; bf16* dst; int C;
  if (z == 0)      { src = wq; dst = wqkvT;                 C = 2048; }
  else if (z == 1) { src = wk; dst = wqkvT + 2048L * 2048;  C = 1024; }
  else if (z == 2) { src = wv; dst = wqkvT + 3072L * 2048;  C = 1024; }
  else             { src = wo; dst = woT;                   C = 2048; }
  int c0 = blockIdx.x * 32, r0 = blockIdx.y * 32;
  if (c0 >= C) return;
  int x = threadIdx.x, y = threadIdx.y;  // 32 x 8
  for (int yy = y; yy < 32; yy += 8)
    tile[yy][x] = (bf16)src[(long)(r0 + yy) * C + c0 + x];
  __syncthreads();
  for (int yy = y; yy < 32; yy += 8)
    dst[(long)(c0 + yy) * 2048 + r0 + x] = tile[x][yy];
}

// ---------------- V transpose per (b,kv): vT[z][d][s] = v[b][s][kv][d] (bf16) ----------------
__global__ __launch_bounds__(256) void vtrans(const bf16* __restrict__ qkv,
                                              bf16* __restrict__ vT) {
  __shared__ bf16 tile[32][33];
  int s0 = blockIdx.x * 32, d0 = blockIdx.y * 32;
  int z = blockIdx.z;
  int b = z >> 3, kv = z & 7;
  const bf16* src = qkv + ((long)b * SDIM) * 4096 + 3072 + kv * 128;
  bf16* dst = vT + (long)z * 128 * 1024;
  int x = threadIdx.x, y = threadIdx.y;
  for (int yy = y; yy < 32; yy += 8)
    tile[yy][x] = src[(long)(s0 + yy) * 4096 + d0 + x];
  __syncthreads();
  for (int yy = y; yy < 32; yy += 8)
    dst[(long)(d0 + yy) * 1024 + s0 + x] = tile[x][yy];
}

// ---------------- GEMM (m97 + XOR swizzle): C = A * Bt^T ----------------
// LDS layout: chunk(row, cc) of 8 elems stored at chunk index row*8 + (cc ^ (row&7)).
// global_load_lds keeps lane-contiguous dest; swizzle applied on global source col.
#define BK 64
template <typename OT>
__global__ __launch_bounds__(256) void gemm_bt_lds(const bf16* __restrict__ A,
                                                   const bf16* __restrict__ Bt,
                                                   OT* __restrict__ C,
                                                   int M, int N, int K) {
  __shared__ bf16 As[128 * BK];
  __shared__ bf16 Bs[128 * BK];
  int m0 = blockIdx.y * 128, n0 = blockIdx.x * 128;
  int t = threadIdx.x;
  int wid = t >> 6, lane = t & 63;
  int wm = (wid >> 1) * 64, wn = (wid & 1) * 64;
  int fm = lane & 15, quad = lane >> 4;
  f32x4 acc[4][4] = {};
  for (int k0 = 0; k0 < K; k0 += BK) {
    for (int p = 0; p < 4; ++p) {
      int idx = p * 256 + t;
      int row = idx >> 3, ccs = idx & 7;
      int gcol = ((ccs ^ (row & 7)) * 8);
      gl_lds16(&A[(long)(m0 + row) * K + k0 + gcol], &As[idx * 8]);
      gl_lds16(&Bt[(long)(n0 + row) * K + k0 + gcol], &Bs[idx * 8]);
    }
    __syncthreads();
    for (int ks = 0; ks < BK; ks += 32) {
      int cc = (ks >> 3) + quad;
      bf16x8 af[4], bfr[4];
      for (int i = 0; i < 4; ++i) {
        int fr = wm + i * 16 + fm;
        af[i] = load8(&As[(fr * 8 + (cc ^ (fr & 7))) * 8]);
      }
      for (int i = 0; i < 4; ++i) {
        int fr = wn + i * 16 + fm;
        bfr[i] = load8(&Bs[(fr * 8 + (cc ^ (fr & 7))) * 8]);
      }
      for (int i = 0; i < 4; ++i)
        for (int j = 0; j < 4; ++j)
          acc[i][j] = __builtin_amdgcn_mfma_f32_16x16x32_bf16(af[i], bfr[j], acc[i][j], 0, 0, 0);
    }
    __syncthreads();
  }
  for (int i = 0; i < 4; ++i)
    for (int j = 0; j < 4; ++j)
      for (int r = 0; r < 4; ++r) {
        int row = m0 + wm + i * 16 + quad * 4 + r;
        int col = n0 + wn + j * 16 + fm;
        C[(long)row * N + col] = (OT)acc[i][j][r];
      }
}

// ---------------- fused RoPE: Q -> q1,q2 (pre-scaled) and K -> k1 ----------------
__global__ __launch_bounds__(256) void rope_qk(const bf16* __restrict__ qkv,
                                               const float* __restrict__ fc,
                                               const float* __restrict__ fs,
                                               bf16* __restrict__ q1,
                                               bf16* __restrict__ q2,
                                               bf16* __restrict__ k1) {
  int idx = blockIdx.x * 256 + threadIdx.x;
  if (idx < 2 * 1024 * 1024) {  // Q part
    int row = idx >> 10;
    int rem = idx & 1023;
    int h = rem >> 6, d = rem & 63;
    int s = row & (SDIM - 1);
    long src = (long)row * 4096 + h * 128 + 2 * d;
    float xr = (float)qkv[src], xi = (float)qkv[src + 1];
    const float scale = 0.08838834764831845f;  // 1/sqrt(128)
    float c = fc[s * 64 + d], sn = fs[s * 64 + d];
    long dst = (long)row * 2048 + h * 128 + 2 * d;
    q1[dst]     = (bf16)((xr * c - xi * sn) * scale);
    q1[dst + 1] = (bf16)((xr * sn + xi * c) * scale);
    float cw = fc[WINDOW * 64 + d], sw = fs[WINDOW * 64 + d];
    q2[dst]     = (bf16)((xr * cw - xi * sw) * scale);
    q2[dst + 1] = (bf16)((xr * sw + xi * cw) * scale);
  } else {  // K part
    int i2 = idx - 2 * 1024 * 1024;
    int row = i2 >> 9;
    int rem = i2 & 511;
    int kv = rem >> 6, d = rem & 63;
    int s = row & (SDIM - 1);
    long src = (long)row * 4096 + 2048 + kv * 128 + 2 * d;
    float xr = (float)qkv[src], xi = (float)qkv[src + 1];
    float c = fc[s * 64 + d], sn = fs[s * 64 + d];
    long dst = (long)row * 1024 + kv * 128 + 2 * d;
    k1[dst]     = (bf16)(xr * c - xi * sn);
    k1[dst + 1] = (bf16)(xr * sn + xi * c);
  }
}

// ---------------- Flash attention v6: 512 wgs, global_load_lds + XOR swizzle ----------------
// Grid (16, NH, B): tile = x (b=0) or 15-x (b=1). One 64-row tile per wg.
// Ks: 128 rows x 16 chunks; chunk(r,cc) at r*16 + (cc^(r&15)). VTs: 128 x 8 chunks,
// chunk(d,cc) at d*8 + (cc^(d&7)). LDS total 58.6 kB -> 2 wgs/CU.
__global__ __launch_bounds__(256) void attn_kernel(const bf16* __restrict__ q1,
                                                   const bf16* __restrict__ q2,
                                                   const bf16* __restrict__ k1,
                                                   const bf16* __restrict__ qkv,
                                                   const bf16* __restrict__ vT,
                                                   bf16* __restrict__ aout) {
  __shared__ bf16 Ks[16384];   // rows 0-63: roped K1; rows 64-127: raw K2
  __shared__ bf16 VTs[8192];   // [d][key] swizzled
  __shared__ bf16 Pl[4][16][72];
  __shared__ float stats[4][16];

  int h = blockIdx.y;
  int b = blockIdx.z;
  int tile = b ? (15 - blockIdx.x) : blockIdx.x;
  int kv = h >> 1;  // NREP = 2
  int t = threadIdx.x;
  int w = t >> 6, lane = t & 63;
  int m = lane & 15, quad = lane >> 4;

  const bf16* k1g0 = k1 + ((long)b * SDIM) * 1024 + kv * 128;
  const bf16* k2g0 = qkv + ((long)b * SDIM) * 4096 + 2048 + kv * 128;
  const bf16* vtg0 = vT + ((long)(b * NKV + kv)) * 128 * 1024;

  int t0 = tile * 64;
  int i0w = t0 + w * 16;  // this wave's 16 query rows

  const bf16* q1p = q1 + ((long)(b * SDIM + i0w + m)) * 2048 + h * 128 + quad * 8;
  const bf16* q2p = q2 + ((long)(b * SDIM + i0w + m)) * 2048 + h * 128 + quad * 8;
  bf16x8 q1f[4], q2f[4];
  for (int kc = 0; kc < 4; ++kc) {
    q1f[kc] = load8(q1p + kc * 32);
    q2f[kc] = load8(q2p + kc * 32);
  }

  f32x4 o[8] = {};
  float mrow = -INFINITY, lrow = 0.f;  // per-lane: row q = i0w + m

  for (int j0 = 0; j0 < t0 + 64; j0 += 64) {
    bool c1 = (j0 + 63 > t0 - WINDOW);
    bool c2 = (j0 <= t0 + 63 - WINDOW);
    __syncthreads();  // prior compute done reading LDS
    for (int p = 0; p < 4; ++p) {
      int idx = p * 256 + t;
      int kr = idx >> 4, kcs = idx & 15;
      int kg = (kcs ^ (kr & 15)) * 8;
      if (c1) gl_lds16(&k1g0[(long)(j0 + kr) * 1024 + kg], &Ks[idx * 8]);
      if (c2) gl_lds16(&k2g0[(long)(j0 + kr) * 4096 + kg], &Ks[8192 + idx * 8]);
      int vd = idx >> 3, vcs = idx & 7;
      int vg = (vcs ^ (vd & 7)) * 8;
      gl_lds16(&vtg0[(long)vd * 1024 + j0 + vg], &VTs[idx * 8]);
    }
    __syncthreads();  // drains vmcnt before compute

    if (j0 < i0w + 16) {  // wave-uniform: block has unmasked keys for this wave
      bool need1 = (j0 + 63 > i0w - WINDOW);
      bool need2 = (j0 <= i0w + 15 - WINDOW);
      f32x4 s1[4] = {}, s2[4] = {};
      if (need1)
        for (int st = 0; st < 4; ++st)
          for (int kc = 0; kc < 4; ++kc) {
            int cc = kc * 4 + quad;
            s1[st] = __builtin_amdgcn_mfma_f32_16x16x32_bf16(
                load8(&Ks[((st * 16 + m) * 16 + (cc ^ m)) * 8]), q1f[kc], s1[st], 0, 0, 0);
          }
      if (need2)
        for (int st = 0; st < 4; ++st)
          for (int kc = 0; kc < 4; ++kc) {
            int cc = kc * 4 + quad;
            s2[st] = __builtin_amdgcn_mfma_f32_16x16x32_bf16(
                load8(&Ks[8192 + ((st * 16 + m) * 16 + (cc ^ m)) * 8]), q2f[kc], s2[st], 0, 0, 0);
          }
      // select + mask; element (st,r): row i = i0w+m, col j = j0+16*st+4*quad+r
      int i = i0w + m;
      float sv[4][4];
      for (int st = 0; st < 4; ++st)
        for (int r = 0; r < 4; ++r) {
          int j = j0 + st * 16 + quad * 4 + r;
          float v;
          if (j > i) v = -INFINITY;
          else if (j > i - WINDOW) v = s1[st][r];
          else v = s2[st][r];
          sv[st][r] = v;
        }
      // row reduce: in-lane (16 vals) + 2 shuffles
      float bm = -INFINITY;
      for (int st = 0; st < 4; ++st)
        for (int r = 0; r < 4; ++r) bm = fmaxf(bm, sv[st][r]);
      bm = fmaxf(bm, __shfl_xor(bm, 16, 64));
      bm = fmaxf(bm, __shfl_xor(bm, 32, 64));
      float mnew = fmaxf(mrow, bm);
      float alpha = exp2f((mrow - mnew) * L2E);
      float rs = 0.f;
      for (int st = 0; st < 4; ++st) {
        bf16x4 pk;
        for (int r = 0; r < 4; ++r) {
          float pvv = exp2f((sv[st][r] - mnew) * L2E);
          rs += pvv;
          pk[r] = (bf16)pvv;
        }
        *(bf16x4*)&Pl[w][m][st * 16 + quad * 4] = pk;  // b64 write
      }
      rs += __shfl_xor(rs, 16, 64);
      rs += __shfl_xor(rs, 32, 64);
      lrow = lrow * alpha + rs;
      mrow = mnew;
      // broadcast alpha to C-layout rows
      if (lane < 16) stats[w][lane] = alpha;
      f32x4 av = *(f32x4*)&stats[w][quad * 4];
      for (int n8 = 0; n8 < 8; ++n8)
        for (int r = 0; r < 4; ++r) o[n8][r] *= av[r];
      // PV: O += P * V
      for (int kc = 0; kc < 2; ++kc) {
        bf16x8 af = load8(&Pl[w][m][kc * 32 + quad * 8]);
        int cc = kc * 4 + quad;
        for (int n8 = 0; n8 < 8; ++n8) {
          int d = n8 * 16 + m;
          o[n8] = __builtin_amdgcn_mfma_f32_16x16x32_bf16(
              af, load8(&VTs[(d * 8 + (cc ^ (d & 7))) * 8]), o[n8], 0, 0, 0);
        }
      }
    }
  }

  // epilogue: redistribute l to C-layout rows, normalize, store
  if (lane < 16) stats[w][lane] = lrow;
  __builtin_amdgcn_s_waitcnt(0);  // lgkmcnt for stats write visibility within wave
  f32x4 lv = *(f32x4*)&stats[w][quad * 4];
  for (int n8 = 0; n8 < 8; ++n8)
    for (int r = 0; r < 4; ++r) {
      int row = i0w + quad * 4 + r;
      float val = o[n8][r] / lv[r];
      aout[((long)(b * SDIM + row)) * 2048 + h * 128 + n8 * 16 + m] = (bf16)val;
    }
}

extern "C" void kernel_launch(void* const* d_in, const int* in_sizes, int n_in,
                              void* d_out, int out_size, void* d_ws, size_t ws_size,
                              hipStream_t stream) {
  const float* x  = (const float*)d_in[0];
  const float* fc = (const float*)d_in[1];
  const float* fs = (const float*)d_in[2];
  const float* wq = (const float*)d_in[3];
  const float* wk = (const float*)d_in[4];
  const float* wv = (const float*)d_in[5];
  const float* wo = (const float*)d_in[6];
  float* out = (float*)d_out;

  // workspace layout (bf16 elements)
  bf16* wqkvT = (bf16*)d_ws;                  // [4096][2048]
  bf16* woT   = wqkvT + 4096L * 2048;         // [2048][2048]
  bf16* xb    = woT + 2048L * 2048;           // [2048][2048]
  bf16* qkv   = xb + 2048L * 2048;            // [2048][4096]
  bf16* q1    = qkv + 2048L * 4096;           // [2048][2048]
  bf16* q2    = q1 + 2048L * 2048;            // [2048][2048]
  bf16* k1b   = q2 + 2048L * 2048;            // [2048][1024]
  bf16* vT    = k1b + 2048L * 1024;           // [16][128][1024]
  bf16* aout  = vT + 2048L * 1024;            // [2048][2048]

  cast_f32_bf16<<<2048, 256, 0, stream>>>(x, xb);
  wtrans_all<<<dim3(64, 64, 4), dim3(32, 8), 0, stream>>>(wq, wk, wv, wo, wqkvT, woT);

  gemm_bt_lds<bf16><<<dim3(32, 16), 256, 0, stream>>>(xb, wqkvT, qkv, 2048, 4096, 2048);

  rope_qk<<<12288, 256, 0, stream>>>(qkv, fc, fs, q1, q2, k1b);
  vtrans<<<dim3(32, 4, 16), dim3(32, 8), 0, stream>>>(qkv, vT);

  attn_kernel<<<dim3(16, 16, 2), 256, 0, stream>>>(q1, q2, k1b, qkv, vT, aout);

  gemm_bt_lds<float><<<dim3(16, 16), 256, 0, stream>>>(aout, woT, out, 2048, 2048, 2048);
}

// Round 7
// 258.193 us; speedup vs baseline: 1.3462x; 1.0069x over previous
//
#include <hip/hip_runtime.h>
#include <hip/hip_bf16.h>

#define BDIM 2
#define SDIM 1024
#define DDIM 2048
#define NH 16
#define NKV 8
#define HD 128
#define WINDOW 256

typedef __bf16 bf16;
typedef __bf16 bf16x4 __attribute__((ext_vector_type(4)));
typedef __bf16 bf16x8 __attribute__((ext_vector_type(8)));
typedef float f32x4 __attribute__((ext_vector_type(4)));

#define L2E 1.44269504088896341f

__device__ inline bf16x8 load8(const bf16* p) { return *reinterpret_cast<const bf16x8*>(p); }

// async global->LDS, 16 B per lane (LDS dest = wave-uniform base + lane*16)
__device__ __forceinline__ void gl_lds16(const bf16* g, bf16* l) {
  __builtin_amdgcn_global_load_lds(
      (__attribute__((address_space(1))) void*)g,
      (__attribute__((address_space(3))) void*)l,
      16, 0, 0);
}

// ---------------- fp32 -> bf16 cast (8 elems/thread) ----------------
__global__ __launch_bounds__(256) void cast_f32_bf16(const float* __restrict__ src,
                                                     bf16* __restrict__ dst) {
  long i = ((long)blockIdx.x * 256 + threadIdx.x) * 8;
  float4 a = *(const float4*)(src + i);
  float4 b = *(const float4*)(src + i + 4);
  bf16x8 o;
  o[0] = (bf16)a.x; o[1] = (bf16)a.y; o[2] = (bf16)a.z; o[3] = (bf16)a.w;
  o[4] = (bf16)b.x; o[5] = (bf16)b.y; o[6] = (bf16)b.z; o[7] = (bf16)b.w;
  *(bf16x8*)(dst + i) = o;
}

// ---------------- fused weight transposes (fp32 in, bf16 out) ----------------
__global__ __launch_bounds__(256) void wtrans_all(const float* __restrict__ wq,
                                                  const float* __restrict__ wk,
                                                  const float* __restrict__ wv,
                                                  const float* __restrict__ wo,
                                                  bf16* __restrict__ wqkvT,
                                                  bf16* __restrict__ woT) {
  __shared__ bf16 tile[32][33];
  int z = blockIdx.z;
  const float* src; bf16* dst; int C;
  if (z == 0)      { src = wq; dst = wqkvT;                 C = 2048; }
  else if (z == 1) { src = wk; dst = wqkvT + 2048L * 2048;  C = 1024; }
  else if (z == 2) { src = wv; dst = wqkvT + 3072L * 2048;  C = 1024; }
  else             { src = wo; dst = woT;                   C = 2048; }
  int c0 = blockIdx.x * 32, r0 = blockIdx.y * 32;
  if (c0 >= C) return;
  int x = threadIdx.x, y = threadIdx.y;  // 32 x 8
  for (int yy = y; yy < 32; yy += 8)
    tile[yy][x] = (bf16)src[(long)(r0 + yy) * C + c0 + x];
  __syncthreads();
  for (int yy = y; yy < 32; yy += 8)
    dst[(long)(c0 + yy) * 2048 + r0 + x] = tile[x][yy];
}

// ---------------- V transpose per (b,kv): vT[z][d][s] = v[b][s][kv][d] (bf16) ----------------
// reads compact v [b][s][kv*128+d] (row stride 1024)
__global__ __launch_bounds__(256) void vtrans(const bf16* __restrict__ vc,
                                              bf16* __restrict__ vT) {
  __shared__ bf16 tile[32][33];
  int s0 = blockIdx.x * 32, d0 = blockIdx.y * 32;
  int z = blockIdx.z;
  int b = z >> 3, kv = z & 7;
  const bf16* src = vc + ((long)b * SDIM) * 1024 + kv * 128;
  bf16* dst = vT + (long)z * 128 * 1024;
  int x = threadIdx.x, y = threadIdx.y;
  for (int yy = y; yy < 32; yy += 8)
    tile[yy][x] = src[(long)(s0 + yy) * 1024 + d0 + x];
  __syncthreads();
  for (int yy = y; yy < 32; yy += 8)
    dst[(long)(d0 + yy) * 1024 + s0 + x] = tile[x][yy];
}

// ---------------- out-proj GEMM (m97 + XOR swizzle): C = A * Bt^T ----------------
#define BK 64
template <typename OT>
__global__ __launch_bounds__(256) void gemm_bt_lds(const bf16* __restrict__ A,
                                                   const bf16* __restrict__ Bt,
                                                   OT* __restrict__ C,
                                                   int M, int N, int K) {
  __shared__ bf16 As[128 * BK];
  __shared__ bf16 Bs[128 * BK];
  int m0 = blockIdx.y * 128, n0 = blockIdx.x * 128;
  int t = threadIdx.x;
  int wid = t >> 6, lane = t & 63;
  int wm = (wid >> 1) * 64, wn = (wid & 1) * 64;
  int fm = lane & 15, quad = lane >> 4;
  f32x4 acc[4][4] = {};
  for (int k0 = 0; k0 < K; k0 += BK) {
    for (int p = 0; p < 4; ++p) {
      int idx = p * 256 + t;
      int row = idx >> 3, ccs = idx & 7;
      int gcol = ((ccs ^ (row & 7)) * 8);
      gl_lds16(&A[(long)(m0 + row) * K + k0 + gcol], &As[idx * 8]);
      gl_lds16(&Bt[(long)(n0 + row) * K + k0 + gcol], &Bs[idx * 8]);
    }
    __syncthreads();
    for (int ks = 0; ks < BK; ks += 32) {
      int cc = (ks >> 3) + quad;
      bf16x8 af[4], bfr[4];
      for (int i = 0; i < 4; ++i) {
        int fr = wm + i * 16 + fm;
        af[i] = load8(&As[(fr * 8 + (cc ^ (fr & 7))) * 8]);
      }
      for (int i = 0; i < 4; ++i) {
        int fr = wn + i * 16 + fm;
        bfr[i] = load8(&Bs[(fr * 8 + (cc ^ (fr & 7))) * 8]);
      }
      for (int i = 0; i < 4; ++i)
        for (int j = 0; j < 4; ++j)
          acc[i][j] = __builtin_amdgcn_mfma_f32_16x16x32_bf16(af[i], bfr[j], acc[i][j], 0, 0, 0);
    }
    __syncthreads();
  }
  for (int i = 0; i < 4; ++i)
    for (int j = 0; j < 4; ++j)
      for (int r = 0; r < 4; ++r) {
        int row = m0 + wm + i * 16 + quad * 4 + r;
        int col = n0 + wn + j * 16 + fm;
        C[(long)row * N + col] = (OT)acc[i][j][r];
      }
}

// ---------------- QKV GEMM with fused RoPE epilogue ----------------
// N=4096: col tiles 0-15 = Q heads (write q1,q2 roped+scaled), 16-23 = KV heads
// (write roped k1 + raw k2), 24-31 = V heads (write compact v).
// RoPE pair (2d,2d+1) = adjacent lanes -> __shfl_xor(v,1).
__global__ __launch_bounds__(256) void gemm_qkv(const bf16* __restrict__ A,
                                                const bf16* __restrict__ Bt,
                                                const float* __restrict__ fc,
                                                const float* __restrict__ fs,
                                                bf16* __restrict__ q1,
                                                bf16* __restrict__ q2,
                                                bf16* __restrict__ k1,
                                                bf16* __restrict__ k2,
                                                bf16* __restrict__ vc) {
  const int K = 2048, N = 4096;
  __shared__ bf16 As[128 * BK];
  __shared__ bf16 Bs[128 * BK];
  int m0 = blockIdx.y * 128, n0 = blockIdx.x * 128;
  int t = threadIdx.x;
  int wid = t >> 6, lane = t & 63;
  int wm = (wid >> 1) * 64, wn = (wid & 1) * 64;
  int fm = lane & 15, quad = lane >> 4;
  f32x4 acc[4][4] = {};
  for (int k0 = 0; k0 < K; k0 += BK) {
    for (int p = 0; p < 4; ++p) {
      int idx = p * 256 + t;
      int row = idx >> 3, ccs = idx & 7;
      int gcol = ((ccs ^ (row & 7)) * 8);
      gl_lds16(&A[(long)(m0 + row) * K + k0 + gcol], &As[idx * 8]);
      gl_lds16(&Bt[(long)(n0 + row) * K + k0 + gcol], &Bs[idx * 8]);
    }
    __syncthreads();
    for (int ks = 0; ks < BK; ks += 32) {
      int cc = (ks >> 3) + quad;
      bf16x8 af[4], bfr[4];
      for (int i = 0; i < 4; ++i) {
        int fr = wm + i * 16 + fm;
        af[i] = load8(&As[(fr * 8 + (cc ^ (fr & 7))) * 8]);
      }
      for (int i = 0; i < 4; ++i) {
        int fr = wn + i * 16 + fm;
        bfr[i] = load8(&Bs[(fr * 8 + (cc ^ (fr & 7))) * 8]);
      }
      for (int i = 0; i < 4; ++i)
        for (int j = 0; j < 4; ++j)
          acc[i][j] = __builtin_amdgcn_mfma_f32_16x16x32_bf16(af[i], bfr[j], acc[i][j], 0, 0, 0);
    }
    __syncthreads();
  }

  int n0h = n0 >> 7;                       // which 128-col head tile
  float sgn = (lane & 1) ? 1.f : -1.f;     // -sin on even cols, +sin on odd
  if (n0h < 16) {  // ---- Q: q1 (per-pos rope), q2 (pos WINDOW rope), both * 1/sqrt(HD)
    const float scale = 0.08838834764831845f;
    for (int j = 0; j < 4; ++j) {
      int col = wn + j * 16 + fm;          // 0..127 within head
      int dp = col >> 1;                   // freq index
      float cw = fc[WINDOW * 64 + dp];
      float sw = fs[WINDOW * 64 + dp] * sgn;
      for (int i = 0; i < 4; ++i)
        for (int r = 0; r < 4; ++r) {
          int row = m0 + wm + i * 16 + quad * 4 + r;
          int s = row & (SDIM - 1);
          float v = acc[i][j][r];
          float pp = __shfl_xor(v, 1, 64);
          float c = fc[s * 64 + dp];
          float sn = fs[s * 64 + dp] * sgn;
          long dst = (long)row * 2048 + n0h * 128 + col;
          q1[dst] = (bf16)((v * c + pp * sn) * scale);
          q2[dst] = (bf16)((v * cw + pp * sw) * scale);
        }
    }
  } else if (n0h < 24) {  // ---- K: roped k1 + raw k2 (compact [row][kv*128+d])
    int kvh = n0h - 16;
    for (int j = 0; j < 4; ++j) {
      int col = wn + j * 16 + fm;
      int dp = col >> 1;
      for (int i = 0; i < 4; ++i)
        for (int r = 0; r < 4; ++r) {
          int row = m0 + wm + i * 16 + quad * 4 + r;
          int s = row & (SDIM - 1);
          float v = acc[i][j][r];
          float pp = __shfl_xor(v, 1, 64);
          float c = fc[s * 64 + dp];
          float sn = fs[s * 64 + dp] * sgn;
          long dst = (long)row * 1024 + kvh * 128 + col;
          k1[dst] = (bf16)(v * c + pp * sn);
          k2[dst] = (bf16)v;
        }
    }
  } else {  // ---- V: compact [row][kv*128+d]
    int vv = n0h - 24;
    for (int j = 0; j < 4; ++j) {
      int col = wn + j * 16 + fm;
      for (int i = 0; i < 4; ++i)
        for (int r = 0; r < 4; ++r) {
          int row = m0 + wm + i * 16 + quad * 4 + r;
          vc[(long)row * 1024 + vv * 128 + col] = (bf16)acc[i][j][r];
        }
    }
  }
}

// ---------------- Flash attention v6: 512 wgs, global_load_lds + XOR swizzle ----------------
// Grid (16, NH, B): tile = x (b=0) or 15-x (b=1). One 64-row tile per wg.
__global__ __launch_bounds__(256) void attn_kernel(const bf16* __restrict__ q1,
                                                   const bf16* __restrict__ q2,
                                                   const bf16* __restrict__ k1,
                                                   const bf16* __restrict__ k2,
                                                   const bf16* __restrict__ vT,
                                                   bf16* __restrict__ aout) {
  __shared__ bf16 Ks[16384];   // rows 0-63: roped K1; rows 64-127: raw K2
  __shared__ bf16 VTs[8192];   // [d][key] swizzled
  __shared__ bf16 Pl[4][16][72];
  __shared__ float stats[4][16];

  int h = blockIdx.y;
  int b = blockIdx.z;
  int tile = b ? (15 - blockIdx.x) : blockIdx.x;
  int kv = h >> 1;  // NREP = 2
  int t = threadIdx.x;
  int w = t >> 6, lane = t & 63;
  int m = lane & 15, quad = lane >> 4;

  const bf16* k1g0 = k1 + ((long)b * SDIM) * 1024 + kv * 128;
  const bf16* k2g0 = k2 + ((long)b * SDIM) * 1024 + kv * 128;
  const bf16* vtg0 = vT + ((long)(b * NKV + kv)) * 128 * 1024;

  int t0 = tile * 64;
  int i0w = t0 + w * 16;  // this wave's 16 query rows

  const bf16* q1p = q1 + ((long)(b * SDIM + i0w + m)) * 2048 + h * 128 + quad * 8;
  const bf16* q2p = q2 + ((long)(b * SDIM + i0w + m)) * 2048 + h * 128 + quad * 8;
  bf16x8 q1f[4], q2f[4];
  for (int kc = 0; kc < 4; ++kc) {
    q1f[kc] = load8(q1p + kc * 32);
    q2f[kc] = load8(q2p + kc * 32);
  }

  f32x4 o[8] = {};
  float mrow = -INFINITY, lrow = 0.f;  // per-lane: row q = i0w + m

  for (int j0 = 0; j0 < t0 + 64; j0 += 64) {
    bool c1 = (j0 + 63 > t0 - WINDOW);
    bool c2 = (j0 <= t0 + 63 - WINDOW);
    __syncthreads();  // prior compute done reading LDS
    for (int p = 0; p < 4; ++p) {
      int idx = p * 256 + t;
      int kr = idx >> 4, kcs = idx & 15;
      int kg = (kcs ^ (kr & 15)) * 8;
      if (c1) gl_lds16(&k1g0[(long)(j0 + kr) * 1024 + kg], &Ks[idx * 8]);
      if (c2) gl_lds16(&k2g0[(long)(j0 + kr) * 1024 + kg], &Ks[8192 + idx * 8]);
      int vd = idx >> 3, vcs = idx & 7;
      int vg = (vcs ^ (vd & 7)) * 8;
      gl_lds16(&vtg0[(long)vd * 1024 + j0 + vg], &VTs[idx * 8]);
    }
    __syncthreads();  // drains vmcnt before compute

    if (j0 < i0w + 16) {  // wave-uniform: block has unmasked keys for this wave
      bool need1 = (j0 + 63 > i0w - WINDOW);
      bool need2 = (j0 <= i0w + 15 - WINDOW);
      f32x4 s1[4] = {}, s2[4] = {};
      if (need1)
        for (int st = 0; st < 4; ++st)
          for (int kc = 0; kc < 4; ++kc) {
            int cc = kc * 4 + quad;
            s1[st] = __builtin_amdgcn_mfma_f32_16x16x32_bf16(
                load8(&Ks[((st * 16 + m) * 16 + (cc ^ m)) * 8]), q1f[kc], s1[st], 0, 0, 0);
          }
      if (need2)
        for (int st = 0; st < 4; ++st)
          for (int kc = 0; kc < 4; ++kc) {
            int cc = kc * 4 + quad;
            s2[st] = __builtin_amdgcn_mfma_f32_16x16x32_bf16(
                load8(&Ks[8192 + ((st * 16 + m) * 16 + (cc ^ m)) * 8]), q2f[kc], s2[st], 0, 0, 0);
          }
      int i = i0w + m;
      float sv[4][4];
      for (int st = 0; st < 4; ++st)
        for (int r = 0; r < 4; ++r) {
          int j = j0 + st * 16 + quad * 4 + r;
          float v;
          if (j > i) v = -INFINITY;
          else if (j > i - WINDOW) v = s1[st][r];
          else v = s2[st][r];
          sv[st][r] = v;
        }
      float bm = -INFINITY;
      for (int st = 0; st < 4; ++st)
        for (int r = 0; r < 4; ++r) bm = fmaxf(bm, sv[st][r]);
      bm = fmaxf(bm, __shfl_xor(bm, 16, 64));
      bm = fmaxf(bm, __shfl_xor(bm, 32, 64));
      float mnew = fmaxf(mrow, bm);
      float alpha = exp2f((mrow - mnew) * L2E);
      float rs = 0.f;
      for (int st = 0; st < 4; ++st) {
        bf16x4 pk;
        for (int r = 0; r < 4; ++r) {
          float pvv = exp2f((sv[st][r] - mnew) * L2E);
          rs += pvv;
          pk[r] = (bf16)pvv;
        }
        *(bf16x4*)&Pl[w][m][st * 16 + quad * 4] = pk;  // b64 write
      }
      rs += __shfl_xor(rs, 16, 64);
      rs += __shfl_xor(rs, 32, 64);
      lrow = lrow * alpha + rs;
      mrow = mnew;
      if (lane < 16) stats[w][lane] = alpha;
      f32x4 av = *(f32x4*)&stats[w][quad * 4];
      for (int n8 = 0; n8 < 8; ++n8)
        for (int r = 0; r < 4; ++r) o[n8][r] *= av[r];
      for (int kc = 0; kc < 2; ++kc) {
        bf16x8 af = load8(&Pl[w][m][kc * 32 + quad * 8]);
        int cc = kc * 4 + quad;
        for (int n8 = 0; n8 < 8; ++n8) {
          int d = n8 * 16 + m;
          o[n8] = __builtin_amdgcn_mfma_f32_16x16x32_bf16(
              af, load8(&VTs[(d * 8 + (cc ^ (d & 7))) * 8]), o[n8], 0, 0, 0);
        }
      }
    }
  }

  if (lane < 16) stats[w][lane] = lrow;
  __builtin_amdgcn_s_waitcnt(0);
  f32x4 lv = *(f32x4*)&stats[w][quad * 4];
  for (int n8 = 0; n8 < 8; ++n8)
    for (int r = 0; r < 4; ++r) {
      int row = i0w + quad * 4 + r;
      float val = o[n8][r] / lv[r];
      aout[((long)(b * SDIM + row)) * 2048 + h * 128 + n8 * 16 + m] = (bf16)val;
    }
}

extern "C" void kernel_launch(void* const* d_in, const int* in_sizes, int n_in,
                              void* d_out, int out_size, void* d_ws, size_t ws_size,
                              hipStream_t stream) {
  const float* x  = (const float*)d_in[0];
  const float* fc = (const float*)d_in[1];
  const float* fs = (const float*)d_in[2];
  const float* wq = (const float*)d_in[3];
  const float* wk = (const float*)d_in[4];
  const float* wv = (const float*)d_in[5];
  const float* wo = (const float*)d_in[6];
  float* out = (float*)d_out;

  // workspace layout (bf16 elements)
  bf16* wqkvT = (bf16*)d_ws;                  // [4096][2048]
  bf16* woT   = wqkvT + 4096L * 2048;         // [2048][2048]
  bf16* xb    = woT + 2048L * 2048;           // [2048][2048]
  bf16* q1    = xb + 2048L * 2048;            // [2048][2048]
  bf16* q2    = q1 + 2048L * 2048;            // [2048][2048]
  bf16* k1b   = q2 + 2048L * 2048;            // [2048][1024]
  bf16* k2b   = k1b + 2048L * 1024;           // [2048][1024]
  bf16* vcb   = k2b + 2048L * 1024;           // [2048][1024]
  bf16* vT    = vcb + 2048L * 1024;           // [16][128][1024]
  bf16* aout  = vT + 2048L * 1024;            // [2048][2048]

  cast_f32_bf16<<<2048, 256, 0, stream>>>(x, xb);
  wtrans_all<<<dim3(64, 64, 4), dim3(32, 8), 0, stream>>>(wq, wk, wv, wo, wqkvT, woT);

  gemm_qkv<<<dim3(32, 16), 256, 0, stream>>>(xb, wqkvT, fc, fs, q1, q2, k1b, k2b, vcb);

  vtrans<<<dim3(32, 4, 16), dim3(32, 8), 0, stream>>>(vcb, vT);

  attn_kernel<<<dim3(16, 16, 2), 256, 0, stream>>>(q1, q2, k1b, k2b, vT, aout);

  gemm_bt_lds<float><<<dim3(16, 16), 256, 0, stream>>>(aout, woT, out, 2048, 2048, 2048);
}

// Round 8
// 244.988 us; speedup vs baseline: 1.4187x; 1.0539x over previous
//
#include <hip/hip_runtime.h>
#include <hip/hip_bf16.h>

#define BDIM 2
#define SDIM 1024
#define DDIM 2048
#define NH 16
#define NKV 8
#define HD 128
#define WINDOW 256

typedef __bf16 bf16;
typedef __bf16 bf16x4 __attribute__((ext_vector_type(4)));
typedef __bf16 bf16x8 __attribute__((ext_vector_type(8)));
typedef float f32x4 __attribute__((ext_vector_type(4)));

#define L2E 1.44269504088896341f

__device__ inline bf16x8 load8(const bf16* p) { return *reinterpret_cast<const bf16x8*>(p); }

// async global->LDS, 16 B per lane (LDS dest = wave-uniform base + lane*16)
__device__ __forceinline__ void gl_lds16(const bf16* g, bf16* l) {
  __builtin_amdgcn_global_load_lds(
      (__attribute__((address_space(1))) void*)g,
      (__attribute__((address_space(3))) void*)l,
      16, 0, 0);
}

// ---------------- fp32 -> bf16 cast (8 elems/thread) ----------------
__global__ __launch_bounds__(256) void cast_f32_bf16(const float* __restrict__ src,
                                                     bf16* __restrict__ dst) {
  long i = ((long)blockIdx.x * 256 + threadIdx.x) * 8;
  float4 a = *(const float4*)(src + i);
  float4 b = *(const float4*)(src + i + 4);
  bf16x8 o;
  o[0] = (bf16)a.x; o[1] = (bf16)a.y; o[2] = (bf16)a.z; o[3] = (bf16)a.w;
  o[4] = (bf16)b.x; o[5] = (bf16)b.y; o[6] = (bf16)b.z; o[7] = (bf16)b.w;
  *(bf16x8*)(dst + i) = o;
}

// ---------------- fused weight transposes (fp32 in, bf16 out) ----------------
__global__ __launch_bounds__(256) void wtrans_all(const float* __restrict__ wq,
                                                  const float* __restrict__ wk,
                                                  const float* __restrict__ wv,
                                                  const float* __restrict__ wo,
                                                  bf16* __restrict__ wqkvT,
                                                  bf16* __restrict__ woT) {
  __shared__ bf16 tile[32][33];
  int z = blockIdx.z;
  const float* src; bf16* dst; int C;
  if (z == 0)      { src = wq; dst = wqkvT;                 C = 2048; }
  else if (z == 1) { src = wk; dst = wqkvT + 2048L * 2048;  C = 1024; }
  else if (z == 2) { src = wv; dst = wqkvT + 3072L * 2048;  C = 1024; }
  else             { src = wo; dst = woT;                   C = 2048; }
  int c0 = blockIdx.x * 32, r0 = blockIdx.y * 32;
  if (c0 >= C) return;
  int x = threadIdx.x, y = threadIdx.y;  // 32 x 8
  for (int yy = y; yy < 32; yy += 8)
    tile[yy][x] = (bf16)src[(long)(r0 + yy) * C + c0 + x];
  __syncthreads();
  for (int yy = y; yy < 32; yy += 8)
    dst[(long)(c0 + yy) * 2048 + r0 + x] = tile[x][yy];
}

// ---------------- out-proj GEMM: 128x64 tiles, grid (N/64, M/128) = 512 blocks ----------------
#define BK 64
__global__ __launch_bounds__(256) void gemm_bt_n64(const bf16* __restrict__ A,
                                                   const bf16* __restrict__ Bt,
                                                   float* __restrict__ C,
                                                   int M, int N, int K) {
  __shared__ bf16 As[128 * BK];
  __shared__ bf16 Bs[64 * BK];
  int m0 = blockIdx.y * 128, n0 = blockIdx.x * 64;
  int t = threadIdx.x;
  int wid = t >> 6, lane = t & 63;
  int wm = (wid >> 1) * 64, wn = (wid & 1) * 32;
  int fm = lane & 15, quad = lane >> 4;
  f32x4 acc[4][2] = {};
  for (int k0 = 0; k0 < K; k0 += BK) {
    for (int p = 0; p < 4; ++p) {
      int idx = p * 256 + t;
      int row = idx >> 3, ccs = idx & 7;
      int gcol = ((ccs ^ (row & 7)) * 8);
      gl_lds16(&A[(long)(m0 + row) * K + k0 + gcol], &As[idx * 8]);
    }
    for (int p = 0; p < 2; ++p) {
      int idx = p * 256 + t;
      int row = idx >> 3, ccs = idx & 7;
      int gcol = ((ccs ^ (row & 7)) * 8);
      gl_lds16(&Bt[(long)(n0 + row) * K + k0 + gcol], &Bs[idx * 8]);
    }
    __syncthreads();
    for (int ks = 0; ks < BK; ks += 32) {
      int cc = (ks >> 3) + quad;
      bf16x8 af[4], bfr[2];
      for (int i = 0; i < 4; ++i) {
        int fr = wm + i * 16 + fm;
        af[i] = load8(&As[(fr * 8 + (cc ^ (fr & 7))) * 8]);
      }
      for (int j = 0; j < 2; ++j) {
        int fr = wn + j * 16 + fm;
        bfr[j] = load8(&Bs[(fr * 8 + (cc ^ (fr & 7))) * 8]);
      }
      for (int i = 0; i < 4; ++i)
        for (int j = 0; j < 2; ++j)
          acc[i][j] = __builtin_amdgcn_mfma_f32_16x16x32_bf16(af[i], bfr[j], acc[i][j], 0, 0, 0);
    }
    __syncthreads();
  }
  for (int i = 0; i < 4; ++i)
    for (int r = 0; r < 4; ++r) {
      int row = m0 + wm + i * 16 + quad * 4 + r;
      for (int j = 0; j < 2; ++j) {
        int col = n0 + wn + j * 16 + fm;
        C[(long)row * N + col] = acc[i][j][r];
      }
    }
}

// ---------------- QKV GEMM with fused RoPE + V-transpose epilogue ----------------
// N=4096: head tiles 0-15 = Q (write q1,q2 roped+scaled), 16-23 = K (roped k1 + raw k2),
// 24-31 = V (transpose via LDS, write vT[kv][d][s] coalesced).
#define VPITCH 130
__global__ __launch_bounds__(256) void gemm_qkv(const bf16* __restrict__ A,
                                                const bf16* __restrict__ Bt,
                                                const float* __restrict__ fc,
                                                const float* __restrict__ fs,
                                                bf16* __restrict__ q1,
                                                bf16* __restrict__ q2,
                                                bf16* __restrict__ k1,
                                                bf16* __restrict__ k2,
                                                bf16* __restrict__ vT) {
  const int K = 2048;
  __shared__ bf16 smem[128 * VPITCH];  // staging: As=smem[0:8192], Bs=smem[8192:16384]
  bf16* As = smem;
  bf16* Bs = smem + 8192;
  int m0 = blockIdx.y * 128, n0 = blockIdx.x * 128;
  int t = threadIdx.x;
  int wid = t >> 6, lane = t & 63;
  int wm = (wid >> 1) * 64, wn = (wid & 1) * 64;
  int fm = lane & 15, quad = lane >> 4;
  f32x4 acc[4][4] = {};
  for (int k0 = 0; k0 < K; k0 += BK) {
    for (int p = 0; p < 4; ++p) {
      int idx = p * 256 + t;
      int row = idx >> 3, ccs = idx & 7;
      int gcol = ((ccs ^ (row & 7)) * 8);
      gl_lds16(&A[(long)(m0 + row) * K + k0 + gcol], &As[idx * 8]);
      gl_lds16(&Bt[(long)(n0 + row) * K + k0 + gcol], &Bs[idx * 8]);
    }
    __syncthreads();
    for (int ks = 0; ks < BK; ks += 32) {
      int cc = (ks >> 3) + quad;
      bf16x8 af[4], bfr[4];
      for (int i = 0; i < 4; ++i) {
        int fr = wm + i * 16 + fm;
        af[i] = load8(&As[(fr * 8 + (cc ^ (fr & 7))) * 8]);
      }
      for (int i = 0; i < 4; ++i) {
        int fr = wn + i * 16 + fm;
        bfr[i] = load8(&Bs[(fr * 8 + (cc ^ (fr & 7))) * 8]);
      }
      for (int i = 0; i < 4; ++i)
        for (int j = 0; j < 4; ++j)
          acc[i][j] = __builtin_amdgcn_mfma_f32_16x16x32_bf16(af[i], bfr[j], acc[i][j], 0, 0, 0);
    }
    __syncthreads();
  }

  int n0h = n0 >> 7;                       // which 128-col head tile
  float sgn = (lane & 1) ? 1.f : -1.f;     // -sin on even cols, +sin on odd
  if (n0h < 16) {  // ---- Q: q1 (per-pos rope), q2 (pos WINDOW rope), both * 1/sqrt(HD)
    const float scale = 0.08838834764831845f;
    float cwj[4], swj[4];
    for (int j = 0; j < 4; ++j) {
      int dp = (wn + j * 16 + fm) >> 1;
      cwj[j] = fc[WINDOW * 64 + dp];
      swj[j] = fs[WINDOW * 64 + dp] * sgn;
    }
    for (int i = 0; i < 4; ++i)
      for (int r = 0; r < 4; ++r) {
        int row = m0 + wm + i * 16 + quad * 4 + r;
        int s = row & (SDIM - 1);
        for (int j = 0; j < 4; ++j) {  // j innermost: 4x32B adjacent stores per row
          int col = wn + j * 16 + fm;
          int dp = col >> 1;
          float v = acc[i][j][r];
          float pp = __shfl_xor(v, 1, 64);
          float c = fc[s * 64 + dp];
          float sn = fs[s * 64 + dp] * sgn;
          long dst = (long)row * 2048 + n0h * 128 + col;
          q1[dst] = (bf16)((v * c + pp * sn) * scale);
          q2[dst] = (bf16)((v * cwj[j] + pp * swj[j]) * scale);
        }
      }
  } else if (n0h < 24) {  // ---- K: roped k1 + raw k2 (compact [row][kv*128+d])
    int kvh = n0h - 16;
    for (int i = 0; i < 4; ++i)
      for (int r = 0; r < 4; ++r) {
        int row = m0 + wm + i * 16 + quad * 4 + r;
        int s = row & (SDIM - 1);
        for (int j = 0; j < 4; ++j) {
          int col = wn + j * 16 + fm;
          int dp = col >> 1;
          float v = acc[i][j][r];
          float pp = __shfl_xor(v, 1, 64);
          float c = fc[s * 64 + dp];
          float sn = fs[s * 64 + dp] * sgn;
          long dst = (long)row * 1024 + kvh * 128 + col;
          k1[dst] = (bf16)(v * c + pp * sn);
          k2[dst] = (bf16)v;
        }
      }
  } else {  // ---- V: transpose 128x128 tile through LDS, write vT[kv][d][s] coalesced
    int vv = n0h - 24;
    for (int i = 0; i < 4; ++i)
      for (int j = 0; j < 4; ++j) {
        int col = wn + j * 16 + fm;
        for (int r = 0; r < 4; ++r) {
          int rl = wm + i * 16 + quad * 4 + r;
          smem[col * VPITCH + rl] = (bf16)acc[i][j][r];
        }
      }
    __syncthreads();
    int s0l = m0 & (SDIM - 1);
    int bq = m0 >> 10;
    bf16* vtg = vT + ((long)(bq * NKV + vv)) * 128 * 1024;
    for (int p = 0; p < 8; ++p) {
      int c = p * 256 + t;
      int d = c >> 4, sc = (c & 15) * 8;
      *(bf16x8*)&vtg[(long)d * 1024 + s0l + sc] = *(bf16x8*)&smem[d * VPITCH + sc];
    }
  }
}

// ---------------- Flash attention v6: 512 wgs, global_load_lds + XOR swizzle ----------------
// Grid (16, NH, B): tile = x (b=0) or 15-x (b=1). One 64-row tile per wg.
__global__ __launch_bounds__(256) void attn_kernel(const bf16* __restrict__ q1,
                                                   const bf16* __restrict__ q2,
                                                   const bf16* __restrict__ k1,
                                                   const bf16* __restrict__ k2,
                                                   const bf16* __restrict__ vT,
                                                   bf16* __restrict__ aout) {
  __shared__ bf16 Ks[16384];   // rows 0-63: roped K1; rows 64-127: raw K2
  __shared__ bf16 VTs[8192];   // [d][key] swizzled
  __shared__ bf16 Pl[4][16][72];
  __shared__ float stats[4][16];

  int h = blockIdx.y;
  int b = blockIdx.z;
  int tile = b ? (15 - blockIdx.x) : blockIdx.x;
  int kv = h >> 1;  // NREP = 2
  int t = threadIdx.x;
  int w = t >> 6, lane = t & 63;
  int m = lane & 15, quad = lane >> 4;

  const bf16* k1g0 = k1 + ((long)b * SDIM) * 1024 + kv * 128;
  const bf16* k2g0 = k2 + ((long)b * SDIM) * 1024 + kv * 128;
  const bf16* vtg0 = vT + ((long)(b * NKV + kv)) * 128 * 1024;

  int t0 = tile * 64;
  int i0w = t0 + w * 16;  // this wave's 16 query rows

  const bf16* q1p = q1 + ((long)(b * SDIM + i0w + m)) * 2048 + h * 128 + quad * 8;
  const bf16* q2p = q2 + ((long)(b * SDIM + i0w + m)) * 2048 + h * 128 + quad * 8;
  bf16x8 q1f[4], q2f[4];
  for (int kc = 0; kc < 4; ++kc) {
    q1f[kc] = load8(q1p + kc * 32);
    q2f[kc] = load8(q2p + kc * 32);
  }

  f32x4 o[8] = {};
  float mrow = -INFINITY, lrow = 0.f;  // per-lane: row q = i0w + m

  for (int j0 = 0; j0 < t0 + 64; j0 += 64) {
    bool c1 = (j0 + 63 > t0 - WINDOW);
    bool c2 = (j0 <= t0 + 63 - WINDOW);
    __syncthreads();  // prior compute done reading LDS
    for (int p = 0; p < 4; ++p) {
      int idx = p * 256 + t;
      int kr = idx >> 4, kcs = idx & 15;
      int kg = (kcs ^ (kr & 15)) * 8;
      if (c1) gl_lds16(&k1g0[(long)(j0 + kr) * 1024 + kg], &Ks[idx * 8]);
      if (c2) gl_lds16(&k2g0[(long)(j0 + kr) * 1024 + kg], &Ks[8192 + idx * 8]);
      int vd = idx >> 3, vcs = idx & 7;
      int vg = (vcs ^ (vd & 7)) * 8;
      gl_lds16(&vtg0[(long)vd * 1024 + j0 + vg], &VTs[idx * 8]);
    }
    __syncthreads();  // drains vmcnt before compute

    if (j0 < i0w + 16) {  // wave-uniform: block has unmasked keys for this wave
      bool need1 = (j0 + 63 > i0w - WINDOW);
      bool need2 = (j0 <= i0w + 15 - WINDOW);
      f32x4 s1[4] = {}, s2[4] = {};
      if (need1)
        for (int st = 0; st < 4; ++st)
          for (int kc = 0; kc < 4; ++kc) {
            int cc = kc * 4 + quad;
            s1[st] = __builtin_amdgcn_mfma_f32_16x16x32_bf16(
                load8(&Ks[((st * 16 + m) * 16 + (cc ^ m)) * 8]), q1f[kc], s1[st], 0, 0, 0);
          }
      if (need2)
        for (int st = 0; st < 4; ++st)
          for (int kc = 0; kc < 4; ++kc) {
            int cc = kc * 4 + quad;
            s2[st] = __builtin_amdgcn_mfma_f32_16x16x32_bf16(
                load8(&Ks[8192 + ((st * 16 + m) * 16 + (cc ^ m)) * 8]), q2f[kc], s2[st], 0, 0, 0);
          }
      int i = i0w + m;
      float sv[4][4];
      for (int st = 0; st < 4; ++st)
        for (int r = 0; r < 4; ++r) {
          int j = j0 + st * 16 + quad * 4 + r;
          float v;
          if (j > i) v = -INFINITY;
          else if (j > i - WINDOW) v = s1[st][r];
          else v = s2[st][r];
          sv[st][r] = v;
        }
      float bm = -INFINITY;
      for (int st = 0; st < 4; ++st)
        for (int r = 0; r < 4; ++r) bm = fmaxf(bm, sv[st][r]);
      bm = fmaxf(bm, __shfl_xor(bm, 16, 64));
      bm = fmaxf(bm, __shfl_xor(bm, 32, 64));
      float mnew = fmaxf(mrow, bm);
      float alpha = exp2f((mrow - mnew) * L2E);
      float rs = 0.f;
      for (int st = 0; st < 4; ++st) {
        bf16x4 pk;
        for (int r = 0; r < 4; ++r) {
          float pvv = exp2f((sv[st][r] - mnew) * L2E);
          rs += pvv;
          pk[r] = (bf16)pvv;
        }
        *(bf16x4*)&Pl[w][m][st * 16 + quad * 4] = pk;  // b64 write
      }
      rs += __shfl_xor(rs, 16, 64);
      rs += __shfl_xor(rs, 32, 64);
      lrow = lrow * alpha + rs;
      mrow = mnew;
      if (lane < 16) stats[w][lane] = alpha;
      f32x4 av = *(f32x4*)&stats[w][quad * 4];
      for (int n8 = 0; n8 < 8; ++n8)
        for (int r = 0; r < 4; ++r) o[n8][r] *= av[r];
      for (int kc = 0; kc < 2; ++kc) {
        bf16x8 af = load8(&Pl[w][m][kc * 32 + quad * 8]);
        int cc = kc * 4 + quad;
        for (int n8 = 0; n8 < 8; ++n8) {
          int d = n8 * 16 + m;
          o[n8] = __builtin_amdgcn_mfma_f32_16x16x32_bf16(
              af, load8(&VTs[(d * 8 + (cc ^ (d & 7))) * 8]), o[n8], 0, 0, 0);
        }
      }
    }
  }

  if (lane < 16) stats[w][lane] = lrow;
  __builtin_amdgcn_s_waitcnt(0);
  f32x4 lv = *(f32x4*)&stats[w][quad * 4];
  for (int n8 = 0; n8 < 8; ++n8)
    for (int r = 0; r < 4; ++r) {
      int row = i0w + quad * 4 + r;
      float val = o[n8][r] / lv[r];
      aout[((long)(b * SDIM + row)) * 2048 + h * 128 + n8 * 16 + m] = (bf16)val;
    }
}

extern "C" void kernel_launch(void* const* d_in, const int* in_sizes, int n_in,
                              void* d_out, int out_size, void* d_ws, size_t ws_size,
                              hipStream_t stream) {
  const float* x  = (const float*)d_in[0];
  const float* fc = (const float*)d_in[1];
  const float* fs = (const float*)d_in[2];
  const float* wq = (const float*)d_in[3];
  const float* wk = (const float*)d_in[4];
  const float* wv = (const float*)d_in[5];
  const float* wo = (const float*)d_in[6];
  float* out = (float*)d_out;

  // workspace layout (bf16 elements)
  bf16* wqkvT = (bf16*)d_ws;                  // [4096][2048]
  bf16* woT   = wqkvT + 4096L * 2048;         // [2048][2048]
  bf16* xb    = woT + 2048L * 2048;           // [2048][2048]
  bf16* q1    = xb + 2048L * 2048;            // [2048][2048]
  bf16* q2    = q1 + 2048L * 2048;            // [2048][2048]
  bf16* k1b   = q2 + 2048L * 2048;            // [2048][1024]
  bf16* k2b   = k1b + 2048L * 1024;           // [2048][1024]
  bf16* vT    = k2b + 2048L * 1024;           // [16][128][1024]
  bf16* aout  = vT + 2048L * 1024;            // [2048][2048]

  cast_f32_bf16<<<2048, 256, 0, stream>>>(x, xb);
  wtrans_all<<<dim3(64, 64, 4), dim3(32, 8), 0, stream>>>(wq, wk, wv, wo, wqkvT, woT);

  gemm_qkv<<<dim3(32, 16), 256, 0, stream>>>(xb, wqkvT, fc, fs, q1, q2, k1b, k2b, vT);

  attn_kernel<<<dim3(16, 16, 2), 256, 0, stream>>>(q1, q2, k1b, k2b, vT, aout);

  gemm_bt_n64<<<dim3(32, 16), 256, 0, stream>>>(aout, woT, out, 2048, 2048, 2048);
}

// Round 9
// 243.133 us; speedup vs baseline: 1.4296x; 1.0076x over previous
//
#include <hip/hip_runtime.h>
#include <hip/hip_bf16.h>

#define BDIM 2
#define SDIM 1024
#define DDIM 2048
#define NH 16
#define NKV 8
#define HD 128
#define WINDOW 256

typedef __bf16 bf16;
typedef __bf16 bf16x4 __attribute__((ext_vector_type(4)));
typedef __bf16 bf16x8 __attribute__((ext_vector_type(8)));
typedef float f32x4 __attribute__((ext_vector_type(4)));

#define L2E 1.44269504088896341f

__device__ inline bf16x8 load8(const bf16* p) { return *reinterpret_cast<const bf16x8*>(p); }

// async global->LDS, 16 B per lane (LDS dest = wave-uniform base + lane*16)
__device__ __forceinline__ void gl_lds16(const bf16* g, bf16* l) {
  __builtin_amdgcn_global_load_lds(
      (__attribute__((address_space(1))) void*)g,
      (__attribute__((address_space(3))) void*)l,
      16, 0, 0);
}

// ---------------- prep: weight transposes (z=0..3) + x cast (z=4) ----------------
__global__ __launch_bounds__(256) void prep(const float* __restrict__ x,
                                            const float* __restrict__ wq,
                                            const float* __restrict__ wk,
                                            const float* __restrict__ wv,
                                            const float* __restrict__ wo,
                                            bf16* __restrict__ xb,
                                            bf16* __restrict__ wqkvT,
                                            bf16* __restrict__ woT) {
  __shared__ bf16 tile[32][33];
  int z = blockIdx.z;
  int tx = threadIdx.x, ty = threadIdx.y;
  if (z == 4) {  // cast x -> xb, 4 elems/thread
    long i = (((long)blockIdx.y * 64 + blockIdx.x) * 256 + ty * 32 + tx) * 4;
    float4 a = *(const float4*)(x + i);
    bf16x4 o;
    o[0] = (bf16)a.x; o[1] = (bf16)a.y; o[2] = (bf16)a.z; o[3] = (bf16)a.w;
    *(bf16x4*)(xb + i) = o;
    return;
  }
  const float* src; bf16* dst; int C;
  if (z == 0)      { src = wq; dst = wqkvT;                 C = 2048; }
  else if (z == 1) { src = wk; dst = wqkvT + 2048L * 2048;  C = 1024; }
  else if (z == 2) { src = wv; dst = wqkvT + 3072L * 2048;  C = 1024; }
  else             { src = wo; dst = woT;                   C = 2048; }
  int c0 = blockIdx.x * 32, r0 = blockIdx.y * 32;
  if (c0 >= C) return;
  for (int yy = ty; yy < 32; yy += 8)
    tile[yy][tx] = (bf16)src[(long)(r0 + yy) * C + c0 + tx];
  __syncthreads();
  for (int yy = ty; yy < 32; yy += 8)
    dst[(long)(c0 + yy) * 2048 + r0 + tx] = tile[tx][yy];
}

// ---------------- out-proj GEMM: 128x64 tiles, grid (N/64, M/128) = 512 blocks ----------------
#define BK 64
__global__ __launch_bounds__(256) void gemm_bt_n64(const bf16* __restrict__ A,
                                                   const bf16* __restrict__ Bt,
                                                   float* __restrict__ C,
                                                   int M, int N, int K) {
  __shared__ bf16 As[128 * BK];
  __shared__ bf16 Bs[64 * BK];
  int m0 = blockIdx.y * 128, n0 = blockIdx.x * 64;
  int t = threadIdx.x;
  int wid = t >> 6, lane = t & 63;
  int wm = (wid >> 1) * 64, wn = (wid & 1) * 32;
  int fm = lane & 15, quad = lane >> 4;
  f32x4 acc[4][2] = {};
  for (int k0 = 0; k0 < K; k0 += BK) {
    for (int p = 0; p < 4; ++p) {
      int idx = p * 256 + t;
      int row = idx >> 3, ccs = idx & 7;
      int gcol = ((ccs ^ (row & 7)) * 8);
      gl_lds16(&A[(long)(m0 + row) * K + k0 + gcol], &As[idx * 8]);
    }
    for (int p = 0; p < 2; ++p) {
      int idx = p * 256 + t;
      int row = idx >> 3, ccs = idx & 7;
      int gcol = ((ccs ^ (row & 7)) * 8);
      gl_lds16(&Bt[(long)(n0 + row) * K + k0 + gcol], &Bs[idx * 8]);
    }
    __syncthreads();
    for (int ks = 0; ks < BK; ks += 32) {
      int cc = (ks >> 3) + quad;
      bf16x8 af[4], bfr[2];
      for (int i = 0; i < 4; ++i) {
        int fr = wm + i * 16 + fm;
        af[i] = load8(&As[(fr * 8 + (cc ^ (fr & 7))) * 8]);
      }
      for (int j = 0; j < 2; ++j) {
        int fr = wn + j * 16 + fm;
        bfr[j] = load8(&Bs[(fr * 8 + (cc ^ (fr & 7))) * 8]);
      }
      for (int i = 0; i < 4; ++i)
        for (int j = 0; j < 2; ++j)
          acc[i][j] = __builtin_amdgcn_mfma_f32_16x16x32_bf16(af[i], bfr[j], acc[i][j], 0, 0, 0);
    }
    __syncthreads();
  }
  for (int i = 0; i < 4; ++i)
    for (int r = 0; r < 4; ++r) {
      int row = m0 + wm + i * 16 + quad * 4 + r;
      for (int j = 0; j < 2; ++j) {
        int col = n0 + wn + j * 16 + fm;
        C[(long)row * N + col] = acc[i][j][r];
      }
    }
}

// ---------------- QKV GEMM with fused epilogue ----------------
// head tiles 0-15 = Q: q0 = scale*acc (raw, no rope).
// 16-23 = K: k1 = R(s)*k, k2 = R(-WINDOW)*k  (s2 = q2.k2_raw == q0.R(-W)k identity)
// 24-31 = V: transpose via LDS, write vT[kv][d][s].
#define VPITCH 130
__global__ __launch_bounds__(256) void gemm_qkv(const bf16* __restrict__ A,
                                                const bf16* __restrict__ Bt,
                                                const float* __restrict__ fc,
                                                const float* __restrict__ fs,
                                                bf16* __restrict__ q0,
                                                bf16* __restrict__ k1,
                                                bf16* __restrict__ k2,
                                                bf16* __restrict__ vT) {
  const int K = 2048;
  __shared__ bf16 smem[128 * VPITCH];  // staging: As=smem[0:8192], Bs=smem[8192:16384]
  bf16* As = smem;
  bf16* Bs = smem + 8192;
  int m0 = blockIdx.y * 128, n0 = blockIdx.x * 128;
  int t = threadIdx.x;
  int wid = t >> 6, lane = t & 63;
  int wm = (wid >> 1) * 64, wn = (wid & 1) * 64;
  int fm = lane & 15, quad = lane >> 4;
  f32x4 acc[4][4] = {};
  for (int k0 = 0; k0 < K; k0 += BK) {
    for (int p = 0; p < 4; ++p) {
      int idx = p * 256 + t;
      int row = idx >> 3, ccs = idx & 7;
      int gcol = ((ccs ^ (row & 7)) * 8);
      gl_lds16(&A[(long)(m0 + row) * K + k0 + gcol], &As[idx * 8]);
      gl_lds16(&Bt[(long)(n0 + row) * K + k0 + gcol], &Bs[idx * 8]);
    }
    __syncthreads();
    for (int ks = 0; ks < BK; ks += 32) {
      int cc = (ks >> 3) + quad;
      bf16x8 af[4], bfr[4];
      for (int i = 0; i < 4; ++i) {
        int fr = wm + i * 16 + fm;
        af[i] = load8(&As[(fr * 8 + (cc ^ (fr & 7))) * 8]);
      }
      for (int i = 0; i < 4; ++i) {
        int fr = wn + i * 16 + fm;
        bfr[i] = load8(&Bs[(fr * 8 + (cc ^ (fr & 7))) * 8]);
      }
      for (int i = 0; i < 4; ++i)
        for (int j = 0; j < 4; ++j)
          acc[i][j] = __builtin_amdgcn_mfma_f32_16x16x32_bf16(af[i], bfr[j], acc[i][j], 0, 0, 0);
    }
    __syncthreads();
  }

  int n0h = n0 >> 7;                       // which 128-col head tile
  if (n0h < 16) {  // ---- Q: raw scaled store (no rope)
    const float scale = 0.08838834764831845f;
    for (int i = 0; i < 4; ++i)
      for (int r = 0; r < 4; ++r) {
        int row = m0 + wm + i * 16 + quad * 4 + r;
        for (int j = 0; j < 4; ++j) {
          int col = wn + j * 16 + fm;
          q0[(long)row * 2048 + n0h * 128 + col] = (bf16)(acc[i][j][r] * scale);
        }
      }
  } else if (n0h < 24) {  // ---- K: k1 = R(s)k, k2 = R(-W)k
    int kvh = n0h - 16;
    float sgn = (lane & 1) ? 1.f : -1.f;   // forward rope sign
    float cwj[4], swj[4];
    for (int j = 0; j < 4; ++j) {
      int dp = (wn + j * 16 + fm) >> 1;
      cwj[j] = fc[WINDOW * 64 + dp];
      swj[j] = fs[WINDOW * 64 + dp] * (-sgn);  // R(-W): sin negated
    }
    for (int i = 0; i < 4; ++i)
      for (int r = 0; r < 4; ++r) {
        int row = m0 + wm + i * 16 + quad * 4 + r;
        int s = row & (SDIM - 1);
        for (int j = 0; j < 4; ++j) {
          int col = wn + j * 16 + fm;
          int dp = col >> 1;
          float v = acc[i][j][r];
          float pp = __shfl_xor(v, 1, 64);
          float c = fc[s * 64 + dp];
          float sn = fs[s * 64 + dp] * sgn;
          long dst = (long)row * 1024 + kvh * 128 + col;
          k1[dst] = (bf16)(v * c + pp * sn);
          k2[dst] = (bf16)(v * cwj[j] + pp * swj[j]);
        }
      }
  } else {  // ---- V: transpose 128x128 tile through LDS, write vT[kv][d][s] coalesced
    int vv = n0h - 24;
    for (int i = 0; i < 4; ++i)
      for (int j = 0; j < 4; ++j) {
        int col = wn + j * 16 + fm;
        for (int r = 0; r < 4; ++r) {
          int rl = wm + i * 16 + quad * 4 + r;
          smem[col * VPITCH + rl] = (bf16)acc[i][j][r];
        }
      }
    __syncthreads();
    int s0l = m0 & (SDIM - 1);
    int bq = m0 >> 10;
    bf16* vtg = vT + ((long)(bq * NKV + vv)) * 128 * 1024;
    for (int p = 0; p < 8; ++p) {
      int c = p * 256 + t;
      int d = c >> 4, sc = (c & 15) * 8;
      *(bf16x8*)&vtg[(long)d * 1024 + s0l + sc] = *(bf16x8*)&smem[d * VPITCH + sc];
    }
  }
}

// ---------------- Flash attention v7: q1 reconstructed in-register from q0 ----------------
// Grid (16, NH, B): tile = x (b=0) or 15-x (b=1). One 64-row tile per wg.
// branch1 (windowed): R(s)q0 . k1;  branch2 (outside window): q0 . k2 (= R(-W)k).
__global__ __launch_bounds__(256) void attn_kernel(const bf16* __restrict__ q0,
                                                   const bf16* __restrict__ k1,
                                                   const bf16* __restrict__ k2,
                                                   const bf16* __restrict__ vT,
                                                   const float* __restrict__ fc,
                                                   const float* __restrict__ fs,
                                                   bf16* __restrict__ aout) {
  __shared__ bf16 Ks[16384];   // rows 0-63: roped K1; rows 64-127: R(-W) K2
  __shared__ bf16 VTs[8192];   // [d][key] swizzled
  __shared__ bf16 Pl[4][16][72];
  __shared__ float stats[4][16];

  int h = blockIdx.y;
  int b = blockIdx.z;
  int tile = b ? (15 - blockIdx.x) : blockIdx.x;
  int kv = h >> 1;  // NREP = 2
  int t = threadIdx.x;
  int w = t >> 6, lane = t & 63;
  int m = lane & 15, quad = lane >> 4;

  const bf16* k1g0 = k1 + ((long)b * SDIM) * 1024 + kv * 128;
  const bf16* k2g0 = k2 + ((long)b * SDIM) * 1024 + kv * 128;
  const bf16* vtg0 = vT + ((long)(b * NKV + kv)) * 128 * 1024;

  int t0 = tile * 64;
  int i0w = t0 + w * 16;  // this wave's 16 query rows

  const bf16* q0p = q0 + ((long)(b * SDIM + i0w + m)) * 2048 + h * 128 + quad * 8;
  bf16x8 q0f[4], q1f[4];
  int srow = i0w + m;
  for (int kc = 0; kc < 4; ++kc) {
    q0f[kc] = load8(q0p + kc * 32);
    for (int p4 = 0; p4 < 4; ++p4) {
      int dp = kc * 16 + quad * 4 + p4;
      float c = fc[srow * 64 + dp], sn = fs[srow * 64 + dp];
      float xr = (float)q0f[kc][2 * p4], xi = (float)q0f[kc][2 * p4 + 1];
      q1f[kc][2 * p4]     = (bf16)(xr * c - xi * sn);
      q1f[kc][2 * p4 + 1] = (bf16)(xr * sn + xi * c);
    }
  }

  f32x4 o[8] = {};
  float mrow = -INFINITY, lrow = 0.f;  // per-lane: row q = i0w + m

  for (int j0 = 0; j0 < t0 + 64; j0 += 64) {
    bool c1 = (j0 + 63 > t0 - WINDOW);
    bool c2 = (j0 <= t0 + 63 - WINDOW);
    __syncthreads();  // prior compute done reading LDS
    for (int p = 0; p < 4; ++p) {
      int idx = p * 256 + t;
      int kr = idx >> 4, kcs = idx & 15;
      int kg = (kcs ^ (kr & 15)) * 8;
      if (c1) gl_lds16(&k1g0[(long)(j0 + kr) * 1024 + kg], &Ks[idx * 8]);
      if (c2) gl_lds16(&k2g0[(long)(j0 + kr) * 1024 + kg], &Ks[8192 + idx * 8]);
      int vd = idx >> 3, vcs = idx & 7;
      int vg = (vcs ^ (vd & 7)) * 8;
      gl_lds16(&vtg0[(long)vd * 1024 + j0 + vg], &VTs[idx * 8]);
    }
    __syncthreads();  // drains vmcnt before compute

    if (j0 < i0w + 16) {  // wave-uniform: block has unmasked keys for this wave
      bool need1 = (j0 + 63 > i0w - WINDOW);
      bool need2 = (j0 <= i0w + 15 - WINDOW);
      f32x4 s1[4] = {}, s2[4] = {};
      if (need1)
        for (int st = 0; st < 4; ++st)
          for (int kc = 0; kc < 4; ++kc) {
            int cc = kc * 4 + quad;
            s1[st] = __builtin_amdgcn_mfma_f32_16x16x32_bf16(
                load8(&Ks[((st * 16 + m) * 16 + (cc ^ m)) * 8]), q1f[kc], s1[st], 0, 0, 0);
          }
      if (need2)
        for (int st = 0; st < 4; ++st)
          for (int kc = 0; kc < 4; ++kc) {
            int cc = kc * 4 + quad;
            s2[st] = __builtin_amdgcn_mfma_f32_16x16x32_bf16(
                load8(&Ks[8192 + ((st * 16 + m) * 16 + (cc ^ m)) * 8]), q0f[kc], s2[st], 0, 0, 0);
          }
      int i = i0w + m;
      float sv[4][4];
      for (int st = 0; st < 4; ++st)
        for (int r = 0; r < 4; ++r) {
          int j = j0 + st * 16 + quad * 4 + r;
          float v;
          if (j > i) v = -INFINITY;
          else if (j > i - WINDOW) v = s1[st][r];
          else v = s2[st][r];
          sv[st][r] = v;
        }
      float bm = -INFINITY;
      for (int st = 0; st < 4; ++st)
        for (int r = 0; r < 4; ++r) bm = fmaxf(bm, sv[st][r]);
      bm = fmaxf(bm, __shfl_xor(bm, 16, 64));
      bm = fmaxf(bm, __shfl_xor(bm, 32, 64));
      float mnew = fmaxf(mrow, bm);
      float alpha = exp2f((mrow - mnew) * L2E);
      float rs = 0.f;
      for (int st = 0; st < 4; ++st) {
        bf16x4 pk;
        for (int r = 0; r < 4; ++r) {
          float pvv = exp2f((sv[st][r] - mnew) * L2E);
          rs += pvv;
          pk[r] = (bf16)pvv;
        }
        *(bf16x4*)&Pl[w][m][st * 16 + quad * 4] = pk;  // b64 write
      }
      rs += __shfl_xor(rs, 16, 64);
      rs += __shfl_xor(rs, 32, 64);
      lrow = lrow * alpha + rs;
      mrow = mnew;
      if (lane < 16) stats[w][lane] = alpha;
      f32x4 av = *(f32x4*)&stats[w][quad * 4];
      for (int n8 = 0; n8 < 8; ++n8)
        for (int r = 0; r < 4; ++r) o[n8][r] *= av[r];
      for (int kc = 0; kc < 2; ++kc) {
        bf16x8 af = load8(&Pl[w][m][kc * 32 + quad * 8]);
        int cc = kc * 4 + quad;
        for (int n8 = 0; n8 < 8; ++n8) {
          int d = n8 * 16 + m;
          o[n8] = __builtin_amdgcn_mfma_f32_16x16x32_bf16(
              af, load8(&VTs[(d * 8 + (cc ^ (d & 7))) * 8]), o[n8], 0, 0, 0);
        }
      }
    }
  }

  if (lane < 16) stats[w][lane] = lrow;
  __builtin_amdgcn_s_waitcnt(0);
  f32x4 lv = *(f32x4*)&stats[w][quad * 4];
  for (int n8 = 0; n8 < 8; ++n8)
    for (int r = 0; r < 4; ++r) {
      int row = i0w + quad * 4 + r;
      float val = o[n8][r] / lv[r];
      aout[((long)(b * SDIM + row)) * 2048 + h * 128 + n8 * 16 + m] = (bf16)val;
    }
}

extern "C" void kernel_launch(void* const* d_in, const int* in_sizes, int n_in,
                              void* d_out, int out_size, void* d_ws, size_t ws_size,
                              hipStream_t stream) {
  const float* x  = (const float*)d_in[0];
  const float* fc = (const float*)d_in[1];
  const float* fs = (const float*)d_in[2];
  const float* wq = (const float*)d_in[3];
  const float* wk = (const float*)d_in[4];
  const float* wv = (const float*)d_in[5];
  const float* wo = (const float*)d_in[6];
  float* out = (float*)d_out;

  // workspace layout (bf16 elements)
  bf16* wqkvT = (bf16*)d_ws;                  // [4096][2048]
  bf16* woT   = wqkvT + 4096L * 2048;         // [2048][2048]
  bf16* xb    = woT + 2048L * 2048;           // [2048][2048]
  bf16* q0b   = xb + 2048L * 2048;            // [2048][2048]
  bf16* k1b   = q0b + 2048L * 2048;           // [2048][1024]
  bf16* k2b   = k1b + 2048L * 1024;           // [2048][1024]
  bf16* vT    = k2b + 2048L * 1024;           // [16][128][1024]
  bf16* aout  = vT + 2048L * 1024;            // [2048][2048]

  prep<<<dim3(64, 64, 5), dim3(32, 8), 0, stream>>>(x, wq, wk, wv, wo, xb, wqkvT, woT);

  gemm_qkv<<<dim3(32, 16), 256, 0, stream>>>(xb, wqkvT, fc, fs, q0b, k1b, k2b, vT);

  attn_kernel<<<dim3(16, 16, 2), 256, 0, stream>>>(q0b, k1b, k2b, vT, fc, fs, aout);

  gemm_bt_n64<<<dim3(32, 16), 256, 0, stream>>>(aout, woT, out, 2048, 2048, 2048);
}